// Round 1
// baseline (128.084 us; speedup 1.0000x reference)
//
#include <hip/hip_runtime.h>

#define NSEG   4194304
#define BLOCK  256
#define ITEMS  16
#define TILE   (BLOCK * ITEMS)     // 4096
#define NTILES (NSEG / TILE)       // 1024
#define WAVES  (BLOCK / 64)        // 4

static_assert(NSEG % TILE == 0, "tile must divide N");

// Segment monoid: T = sum of angles, C/S = sum of cos/sin of tile-local
// inclusive cumulative angle. combine(a, b) = "a followed by b".
// Inputs by value (safe to alias outputs).
__device__ __forceinline__ void combineSeg(float aT, float aC, float aS,
                                           float bT, float bC, float bS,
                                           float& oT, float& oC, float& oS) {
    float s, c;
    __sincosf(aT, &s, &c);
    oT = aT + bT;
    oC = aC + c * bC - s * bS;
    oS = aS + s * bC + c * bS;
}

// ---------------- K1: per-tile (T, C, S) summaries ----------------
__global__ __launch_bounds__(BLOCK) void k_tilesum(
        const float* __restrict__ vec, const float* __restrict__ vec2,
        float* __restrict__ ws) {
    const int curve = blockIdx.y;
    const float* __restrict__ v = curve ? vec2 : vec;
    const int tile = blockIdx.x;

    const float4* __restrict__ p =
        reinterpret_cast<const float4*>(v + (size_t)tile * TILE) +
        (size_t)threadIdx.x * (ITEMS / 4);
    float vals[ITEMS];
#pragma unroll
    for (int q = 0; q < ITEMS / 4; ++q) {
        float4 a = p[q];
        vals[q * 4 + 0] = a.x; vals[q * 4 + 1] = a.y;
        vals[q * 4 + 2] = a.z; vals[q * 4 + 3] = a.w;
    }
    float tsum = 0.f;
#pragma unroll
    for (int k = 0; k < ITEMS; ++k) tsum += vals[k];

    // block exclusive scan of per-thread angle sums
    const int lane = threadIdx.x & 63;
    const int wave = threadIdx.x >> 6;
    float incl = tsum;
#pragma unroll
    for (int d = 1; d < 64; d <<= 1) {
        float o = __shfl_up(incl, d, 64);
        if (lane >= d) incl += o;
    }
    __shared__ float sW[WAVES];
    if (lane == 63) sW[wave] = incl;
    __syncthreads();
    float wpre = 0.f, tot = 0.f;
#pragma unroll
    for (int w = 0; w < WAVES; ++w) {
        float t = sW[w];
        if (w < wave) wpre += t;
        tot += t;
    }
    const float excl = wpre + incl - tsum;

    // tile-local inclusive angles -> C, S partial sums
    float run = excl, C = 0.f, S = 0.f;
#pragma unroll
    for (int k = 0; k < ITEMS; ++k) {
        run += vals[k];
        float s, c;
        __sincosf(run, &s, &c);
        C += c; S += s;
    }
#pragma unroll
    for (int d = 32; d > 0; d >>= 1) {
        C += __shfl_down(C, d, 64);
        S += __shfl_down(S, d, 64);
    }
    __shared__ float sC[WAVES], sS[WAVES];
    if (lane == 0) { sC[wave] = C; sS[wave] = S; }
    __syncthreads();
    if (threadIdx.x == 0) {
        float Ct = 0.f, St = 0.f;
#pragma unroll
        for (int w = 0; w < WAVES; ++w) { Ct += sC[w]; St += sS[w]; }
        float* tT = ws + (size_t)(0 * 2 + curve) * NTILES;
        float* tC = ws + (size_t)(1 * 2 + curve) * NTILES;
        float* tS = ws + (size_t)(2 * 2 + curve) * NTILES;
        tT[tile] = tot; tC[tile] = Ct; tS[tile] = St;
    }
}

// ---------------- K2: scan tile summaries with the custom monoid ----------------
__global__ __launch_bounds__(1024) void k_scan(
        const float* __restrict__ the0, const float* __restrict__ the02,
        const float* __restrict__ PS, const float* __restrict__ PE,
        const float* __restrict__ dl, float* __restrict__ ws) {
    const int curve = blockIdx.x;
    float* tT  = ws + (size_t)(0 * 2 + curve) * NTILES;
    float* tC  = ws + (size_t)(1 * 2 + curve) * NTILES;
    float* tS  = ws + (size_t)(2 * 2 + curve) * NTILES;
    float* thp = ws + (size_t)(3 * 2 + curve) * NTILES;
    float* ppx = ws + (size_t)(4 * 2 + curve) * NTILES;
    float* ppy = ws + (size_t)(5 * 2 + curve) * NTILES;

    const int i = threadIdx.x;                 // one tile per thread, 1024 tiles
    float T = tT[i], C = tC[i], S = tS[i];
    const int lane = i & 63, wave = i >> 6;

#pragma unroll
    for (int d = 1; d < 64; d <<= 1) {
        float oT = __shfl_up(T, d, 64);
        float oC = __shfl_up(C, d, 64);
        float oS = __shfl_up(S, d, 64);
        if (lane >= d) combineSeg(oT, oC, oS, T, C, S, T, C, S);
    }
    __shared__ float wT[16], wC[16], wS[16];
    if (lane == 63) { wT[wave] = T; wC[wave] = C; wS[wave] = S; }
    __syncthreads();
    if (i == 0) {  // exclusive scan of 16 wave totals (serial, trivial)
        float pT = 0.f, pC = 0.f, pS = 0.f;
#pragma unroll
        for (int w = 0; w < 16; ++w) {
            float aT = wT[w], aC = wC[w], aS = wS[w];
            wT[w] = pT; wC[w] = pC; wS[w] = pS;
            combineSeg(pT, pC, pS, aT, aC, aS, pT, pC, pS);
        }
    }
    __syncthreads();
    combineSeg(wT[wave], wC[wave], wS[wave], T, C, S, T, C, S);

    __shared__ float iT[1024], iC[1024], iS[1024];
    iT[i] = T; iC[i] = C; iS[i] = S;
    __syncthreads();
    float exT = 0.f, exC = 0.f, exS = 0.f;
    if (i > 0) { exT = iT[i - 1]; exC = iC[i - 1]; exS = iS[i - 1]; }

    const float t0 = curve ? the02[0] : the0[0];
    const float sx = curve ? PE[0] : PS[0];
    const float sy = curve ? PE[1] : PS[1];
    const float dlv = dl[0];
    float s0, c0;
    __sincosf(t0, &s0, &c0);
    thp[i] = t0 + exT;
    ppx[i] = sx + dlv * (c0 * exC - s0 * exS);
    ppy[i] = sy + dlv * (s0 * exC + c0 * exS);
}

// ---------------- K3: recompute intra-tile, emit positions ----------------
__global__ __launch_bounds__(BLOCK) void k_emit(
        const float* __restrict__ vec, const float* __restrict__ vec2,
        const float* __restrict__ PS, const float* __restrict__ PE,
        const float* __restrict__ dl,
        const float* __restrict__ ws, float* __restrict__ out) {
    const int curve = blockIdx.y;
    const float* __restrict__ v = curve ? vec2 : vec;
    const int tile = blockIdx.x;
    const float* thp = ws + (size_t)(3 * 2 + curve) * NTILES;
    const float* ppx = ws + (size_t)(4 * 2 + curve) * NTILES;
    const float* ppy = ws + (size_t)(5 * 2 + curve) * NTILES;

    const float4* __restrict__ p =
        reinterpret_cast<const float4*>(v + (size_t)tile * TILE) +
        (size_t)threadIdx.x * (ITEMS / 4);
    float vals[ITEMS];
#pragma unroll
    for (int q = 0; q < ITEMS / 4; ++q) {
        float4 a = p[q];
        vals[q * 4 + 0] = a.x; vals[q * 4 + 1] = a.y;
        vals[q * 4 + 2] = a.z; vals[q * 4 + 3] = a.w;
    }
    float tsum = 0.f;
#pragma unroll
    for (int k = 0; k < ITEMS; ++k) tsum += vals[k];

    const int lane = threadIdx.x & 63;
    const int wave = threadIdx.x >> 6;
    float incl = tsum;
#pragma unroll
    for (int d = 1; d < 64; d <<= 1) {
        float o = __shfl_up(incl, d, 64);
        if (lane >= d) incl += o;
    }
    __shared__ float sW[WAVES];
    if (lane == 63) sW[wave] = incl;
    __syncthreads();
    float wpre = 0.f;
#pragma unroll
    for (int w = 0; w < WAVES; ++w) {
        float t = sW[w];
        if (w < wave) wpre += t;
    }
    const float angExcl = wpre + incl - tsum;

    // absolute thetas; per-thread step sums
    const float base = thp[tile] + angExcl;
    float cs[ITEMS], sn[ITEMS];
    float run = base, sxs = 0.f, sys = 0.f;
#pragma unroll
    for (int k = 0; k < ITEMS; ++k) {
        run += vals[k];
        __sincosf(run, &sn[k], &cs[k]);
        sxs += cs[k]; sys += sn[k];
    }

    // block exclusive scan of per-thread (sum cos, sum sin)
    float ix = sxs, iy = sys;
#pragma unroll
    for (int d = 1; d < 64; d <<= 1) {
        float ox = __shfl_up(ix, d, 64);
        float oy = __shfl_up(iy, d, 64);
        if (lane >= d) { ix += ox; iy += oy; }
    }
    __shared__ float sWx[WAVES], sWy[WAVES];
    if (lane == 63) { sWx[wave] = ix; sWy[wave] = iy; }
    __syncthreads();
    float wpx = 0.f, wpy = 0.f;
#pragma unroll
    for (int w = 0; w < WAVES; ++w) {
        if (w < wave) { wpx += sWx[w]; wpy += sWy[w]; }
    }
    const float ex = wpx + ix - sxs;
    const float ey = wpy + iy - sys;

    const float dlv = dl[0];
    float px = ppx[tile] + dlv * ex;
    float py = ppy[tile] + dlv * ey;

    float2* __restrict__ o2 =
        reinterpret_cast<float2*>(out) + (size_t)curve * (NSEG + 1);
    const size_t gbase = (size_t)tile * TILE + (size_t)threadIdx.x * ITEMS;
#pragma unroll
    for (int k = 0; k < ITEMS; ++k) {
        px += dlv * cs[k];
        py += dlv * sn[k];
        o2[gbase + k + 1] = make_float2(px, py);
    }
    if (tile == 0 && threadIdx.x == 0) {
        o2[0] = make_float2(curve ? PE[0] : PS[0], curve ? PE[1] : PS[1]);
    }
}

extern "C" void kernel_launch(void* const* d_in, const int* in_sizes, int n_in,
                              void* d_out, int out_size, void* d_ws, size_t ws_size,
                              hipStream_t stream) {
    const float* vec   = (const float*)d_in[0];
    const float* vec2  = (const float*)d_in[1];
    const float* the0  = (const float*)d_in[2];
    const float* the02 = (const float*)d_in[3];
    const float* PS    = (const float*)d_in[4];
    const float* PE    = (const float*)d_in[5];
    const float* dl    = (const float*)d_in[6];
    float* out = (float*)d_out;
    float* ws  = (float*)d_ws;   // needs 6 * 2 * NTILES floats = 48 KB

    dim3 grid(NTILES, 2);
    k_tilesum<<<grid, BLOCK, 0, stream>>>(vec, vec2, ws);
    k_scan<<<dim3(2), 1024, 0, stream>>>(the0, the02, PS, PE, dl, ws);
    k_emit<<<grid, BLOCK, 0, stream>>>(vec, vec2, PS, PE, dl, ws, out);
}